// Round 1
// baseline (1210.870 us; speedup 1.0000x reference)
//
#include <hip/hip_runtime.h>
#include <math.h>

#define B_   8
#define T_   2048
#define NE_  384
#define HQ_  8
#define HKV_ 2
#define D_   48
#define DH_  24   // D/2

// ---------------- kernel 0: RoPE cos/sin table ----------------
__global__ void rope_tab_kernel(float* __restrict__ ct, float* __restrict__ st) {
    int i = blockIdx.x * 256 + threadIdx.x;
    if (i >= T_ * DH_) return;
    int t = i / DH_, j = i - t * DH_;
    double inv = pow(10000.0, -(double)(2 * j) / (double)D_);
    double ang = (double)t * inv;
    ct[i] = (float)cos(ang);
    st[i] = (float)sin(ang);
}

// ---------------- kernel 1: fused QKV GEMM + RoPE ----------------
// C[16384 x 576] = X[16384 x 384] @ [wq | wk | wv]; epilogue applies RoPE to
// q/k cols and scatters to q_ws[b,hq,t,d], k_ws[b,hkv,t,d], v_ws[b,hkv,t,d].
__global__ __launch_bounds__(256) void qkv_rope_kernel(
    const float* __restrict__ x, const float* __restrict__ wq,
    const float* __restrict__ wk, const float* __restrict__ wv,
    const float* __restrict__ ct, const float* __restrict__ st,
    float* __restrict__ q_ws, float* __restrict__ k_ws, float* __restrict__ v_ws)
{
    const int tid = threadIdx.x;
    const int n0 = blockIdx.x * 64;   // 9 col tiles (576)
    const int m0 = blockIdx.y * 64;   // 256 row tiles
    __shared__ float As[32][64];      // A transposed: As[k][m]
    __shared__ float Bs[32][68];      // Bs[k][n], padded
    float acc[4][4] = {};
    const int tm0 = (tid >> 4) << 2;
    const int tn0 = (tid & 15) << 2;

    for (int kt = 0; kt < 384; kt += 32) {
#pragma unroll
        for (int p = 0; p < 2; ++p) {
            int f = tid + p * 256;
            int m = f & 63, kg = f >> 6;            // kg: 0..7
            float4 a4 = *(const float4*)&x[(size_t)(m0 + m) * NE_ + kt + kg * 4];
            As[kg * 4 + 0][m] = a4.x; As[kg * 4 + 1][m] = a4.y;
            As[kg * 4 + 2][m] = a4.z; As[kg * 4 + 3][m] = a4.w;
        }
#pragma unroll
        for (int p = 0; p < 2; ++p) {
            int f = tid + p * 256;
            int kk = f >> 4, ncg = f & 15;
            int n = n0 + ncg * 4;
            int kr = kt + kk;
            float4 b4;
            if (n < 384)      b4 = *(const float4*)&wq[(size_t)kr * 384 + n];
            else if (n < 480) b4 = *(const float4*)&wk[(size_t)kr * 96 + (n - 384)];
            else              b4 = *(const float4*)&wv[(size_t)kr * 96 + (n - 480)];
            *(float4*)&Bs[kk][ncg * 4] = b4;
        }
        __syncthreads();
#pragma unroll
        for (int kk = 0; kk < 32; ++kk) {
            float4 a4 = *(const float4*)&As[kk][tm0];
            float4 b4 = *(const float4*)&Bs[kk][tn0];
            float a[4] = {a4.x, a4.y, a4.z, a4.w};
            float b[4] = {b4.x, b4.y, b4.z, b4.w};
#pragma unroll
            for (int i = 0; i < 4; ++i)
#pragma unroll
                for (int j = 0; j < 4; ++j)
                    acc[i][j] += a[i] * b[j];
        }
        __syncthreads();
    }

    // epilogue: RoPE + scatter (cols come in even/odd pairs inside each quad)
#pragma unroll
    for (int i = 0; i < 4; ++i) {
        int m = m0 + tm0 + i;
        int b = m >> 11;          // /T_
        int t = m & 2047;
#pragma unroll
        for (int jp = 0; jp < 4; jp += 2) {
            int n = n0 + tn0 + jp;
            float e = acc[i][jp], o = acc[i][jp + 1];
            if (n < 384) {                       // q
                int h = n / 48, d = n % 48, fi = d >> 1;
                float c = ct[t * DH_ + fi], s = st[t * DH_ + fi];
                size_t base = ((size_t)(b * HQ_ + h) * T_ + t) * D_ + d;
                q_ws[base]     = e * c - o * s;
                q_ws[base + 1] = e * s + o * c;
            } else if (n < 480) {                // k
                int nn = n - 384;
                int h = nn / 48, d = nn % 48, fi = d >> 1;
                float c = ct[t * DH_ + fi], s = st[t * DH_ + fi];
                size_t base = ((size_t)(b * HKV_ + h) * T_ + t) * D_ + d;
                k_ws[base]     = e * c - o * s;
                k_ws[base + 1] = e * s + o * c;
            } else {                             // v (no rope)
                int nn = n - 480;
                int h = nn / 48, d = nn % 48;
                size_t base = ((size_t)(b * HKV_ + h) * T_ + t) * D_ + d;
                v_ws[base]     = e;
                v_ws[base + 1] = o;
            }
        }
    }
}

// ---------------- kernel 2: flash attention (causal GQA) ----------------
// Block = (qtile, hq, b), 256 threads. Br=Bc=64. S kept TRANSPOSED in LDS
// (St[kcol][qrow]) so the PV phase reads both P and V as float4.
__global__ __launch_bounds__(256) void attn_kernel(
    const float* __restrict__ q_ws, const float* __restrict__ k_ws,
    const float* __restrict__ v_ws, float* __restrict__ ao)
{
    const int tid = threadIdx.x;
    const int qt = blockIdx.x;          // 0..31
    const int h  = blockIdx.y;          // 0..7
    const int b  = blockIdx.z;          // 0..7
    const int hk = h >> 2;              // GROUP=4

    __shared__ float Qs[48][64];        // transposed: Qs[d][qrow]
    __shared__ float Ks[48][64];        // transposed: Ks[d][krow]
    __shared__ float Vs[64][48];        // Vs[krow][d]
    __shared__ float St[64][68];        // St[kcol][qrow], padded stride 68
    __shared__ float mS[64], lS[64], aS[64];

    const float scale = 0.14433756729740643f;   // 1/sqrt(48)

    // stage Q (transposed, pre-scaled)
    {
        const float* qb = q_ws + ((size_t)(b * HQ_ + h) * T_ + qt * 64) * D_;
#pragma unroll
        for (int p = 0; p < 3; ++p) {
            int f = tid + p * 256;               // 0..767
            int m = f & 63, kg = f >> 6;         // kg: 0..11
            float4 v4 = *(const float4*)&qb[m * 48 + kg * 4];
            Qs[kg * 4 + 0][m] = v4.x * scale; Qs[kg * 4 + 1][m] = v4.y * scale;
            Qs[kg * 4 + 2][m] = v4.z * scale; Qs[kg * 4 + 3][m] = v4.w * scale;
        }
    }
    if (tid < 64) { mS[tid] = -1e30f; lS[tid] = 0.0f; }

    const int tm0 = (tid >> 4) << 2;    // q-row quad (QK phase)
    const int tn0 = (tid & 15) << 2;    // k-col quad (QK phase)
    const int rg4 = (tid & 15) << 2;    // q-row quad (PV phase, tid<192)
    const int cg4 = (tid >> 4) << 2;    // d quad   (PV phase)
    float o[4][4] = {};

    for (int jt = 0; jt <= qt; ++jt) {
        __syncthreads();   // prev-iter PV readers done before restaging
        {
            const float* kb = k_ws + ((size_t)(b * HKV_ + hk) * T_ + jt * 64) * D_;
            const float* vb = v_ws + ((size_t)(b * HKV_ + hk) * T_ + jt * 64) * D_;
#pragma unroll
            for (int p = 0; p < 3; ++p) {
                int f = tid + p * 256;
                int m = f & 63, kg = f >> 6;
                float4 k4 = *(const float4*)&kb[m * 48 + kg * 4];
                Ks[kg * 4 + 0][m] = k4.x; Ks[kg * 4 + 1][m] = k4.y;
                Ks[kg * 4 + 2][m] = k4.z; Ks[kg * 4 + 3][m] = k4.w;
                float4 v4 = *(const float4*)&vb[m * 48 + kg * 4];
                *(float4*)&Vs[m][kg * 4] = v4;
            }
        }
        __syncthreads();

        // S = (Q*scale) K^T, 4x4 microtile, write transposed + causal mask
        {
            float sacc[4][4] = {};
#pragma unroll 12
            for (int kk = 0; kk < 48; ++kk) {
                float4 qa = *(const float4*)&Qs[kk][tm0];
                float4 kv = *(const float4*)&Ks[kk][tn0];
                float a[4] = {qa.x, qa.y, qa.z, qa.w};
                float c[4] = {kv.x, kv.y, kv.z, kv.w};
#pragma unroll
                for (int i = 0; i < 4; ++i)
#pragma unroll
                    for (int j = 0; j < 4; ++j)
                        sacc[i][j] += a[i] * c[j];
            }
#pragma unroll
            for (int i = 0; i < 4; ++i) {
                int qg = qt * 64 + tm0 + i;
#pragma unroll
                for (int j = 0; j < 4; ++j) {
                    int kg2 = jt * 64 + tn0 + j;
                    St[tn0 + j][tm0 + i] = (kg2 <= qg) ? sacc[i][j] : -1e30f;
                }
            }
        }
        __syncthreads();

        // online softmax: 4 threads per q-row
        {
            int r = tid >> 2, cq = tid & 3;
            float sv[16], mloc = -1e30f;
#pragma unroll
            for (int u = 0; u < 16; ++u) {
                sv[u] = St[cq * 16 + u][r];
                mloc = fmaxf(mloc, sv[u]);
            }
            mloc = fmaxf(mloc, __shfl_xor(mloc, 1));
            mloc = fmaxf(mloc, __shfl_xor(mloc, 2));
            float mold = mS[r];
            float mnew = fmaxf(mold, mloc);
            float psum = 0.0f;
#pragma unroll
            for (int u = 0; u < 16; ++u) {
                float p = __expf(sv[u] - mnew);
                St[cq * 16 + u][r] = p;
                psum += p;
            }
            psum += __shfl_xor(psum, 1);
            psum += __shfl_xor(psum, 2);
            float alpha = __expf(mold - mnew);
            if (cq == 0) {
                mS[r] = mnew;
                lS[r] = alpha * lS[r] + psum;
                aS[r] = alpha;
            }
        }
        __syncthreads();

        // O = alpha*O + P @ V  (192 threads, 4x4 microtile, all-b128 reads)
        if (tid < 192) {
            float a0 = aS[rg4], a1 = aS[rg4 + 1], a2 = aS[rg4 + 2], a3 = aS[rg4 + 3];
#pragma unroll
            for (int j = 0; j < 4; ++j) {
                o[0][j] *= a0; o[1][j] *= a1; o[2][j] *= a2; o[3][j] *= a3;
            }
#pragma unroll 8
            for (int s = 0; s < 64; ++s) {
                float4 p4 = *(const float4*)&St[s][rg4];
                float4 v4 = *(const float4*)&Vs[s][cg4];
                float p[4] = {p4.x, p4.y, p4.z, p4.w};
                float v[4] = {v4.x, v4.y, v4.z, v4.w};
#pragma unroll
                for (int i = 0; i < 4; ++i)
#pragma unroll
                    for (int j = 0; j < 4; ++j)
                        o[i][j] += p[i] * v[j];
            }
        }
    }

    // epilogue: divide by l, write ao[b, t, h*48 + d]
    if (tid < 192) {
#pragma unroll
        for (int i = 0; i < 4; ++i) {
            int t = qt * 64 + rg4 + i;
            float li = 1.0f / lS[rg4 + i];
            float4 r4 = make_float4(o[i][0] * li, o[i][1] * li, o[i][2] * li, o[i][3] * li);
            *(float4*)&ao[((size_t)b * T_ + t) * NE_ + h * D_ + cg4] = r4;
        }
    }
}

// ---------------- kernel 3: out projection + bias ----------------
__global__ __launch_bounds__(256) void out_proj_kernel(
    const float* __restrict__ A, const float* __restrict__ W,
    const float* __restrict__ bias, float* __restrict__ out)
{
    const int tid = threadIdx.x;
    const int n0 = blockIdx.x * 64;   // 6 col tiles
    const int m0 = blockIdx.y * 64;   // 256 row tiles
    __shared__ float As[32][64];
    __shared__ float Bs[32][68];
    float acc[4][4] = {};
    const int tm0 = (tid >> 4) << 2;
    const int tn0 = (tid & 15) << 2;

    for (int kt = 0; kt < 384; kt += 32) {
#pragma unroll
        for (int p = 0; p < 2; ++p) {
            int f = tid + p * 256;
            int m = f & 63, kg = f >> 6;
            float4 a4 = *(const float4*)&A[(size_t)(m0 + m) * 384 + kt + kg * 4];
            As[kg * 4 + 0][m] = a4.x; As[kg * 4 + 1][m] = a4.y;
            As[kg * 4 + 2][m] = a4.z; As[kg * 4 + 3][m] = a4.w;
        }
#pragma unroll
        for (int p = 0; p < 2; ++p) {
            int f = tid + p * 256;
            int kk = f >> 4, ncg = f & 15;
            float4 b4 = *(const float4*)&W[(size_t)(kt + kk) * 384 + n0 + ncg * 4];
            *(float4*)&Bs[kk][ncg * 4] = b4;
        }
        __syncthreads();
#pragma unroll
        for (int kk = 0; kk < 32; ++kk) {
            float4 a4 = *(const float4*)&As[kk][tm0];
            float4 b4 = *(const float4*)&Bs[kk][tn0];
            float a[4] = {a4.x, a4.y, a4.z, a4.w};
            float b[4] = {b4.x, b4.y, b4.z, b4.w};
#pragma unroll
            for (int i = 0; i < 4; ++i)
#pragma unroll
                for (int j = 0; j < 4; ++j)
                    acc[i][j] += a[i] * b[j];
        }
        __syncthreads();
    }

    float4 bv = *(const float4*)&bias[n0 + tn0];
#pragma unroll
    for (int i = 0; i < 4; ++i) {
        size_t row = m0 + tm0 + i;
        float4 r = make_float4(acc[i][0] + bv.x, acc[i][1] + bv.y,
                               acc[i][2] + bv.z, acc[i][3] + bv.w);
        *(float4*)&out[row * 384 + n0 + tn0] = r;
    }
}

// ---------------- launcher ----------------
extern "C" void kernel_launch(void* const* d_in, const int* in_sizes, int n_in,
                              void* d_out, int out_size, void* d_ws, size_t ws_size,
                              hipStream_t stream) {
    const float* x  = (const float*)d_in[0];
    const float* wq = (const float*)d_in[1];
    const float* wk = (const float*)d_in[2];
    const float* wv = (const float*)d_in[3];
    const float* wo = (const float*)d_in[4];
    const float* bo = (const float*)d_in[5];
    float* out = (float*)d_out;

    float* ws = (float*)d_ws;
    float* ct   = ws;                       // 2048*24
    float* st   = ct + T_ * DH_;            // 2048*24
    float* q_ws = st + T_ * DH_;            // 8*8*2048*48  = 6291456
    float* k_ws = q_ws + (size_t)B_ * HQ_  * T_ * D_;   // 1572864
    float* v_ws = k_ws + (size_t)B_ * HKV_ * T_ * D_;   // 1572864
    float* ao   = v_ws + (size_t)B_ * HKV_ * T_ * D_;   // 6291456
    // total ws: ~63.3 MB of float

    hipLaunchKernelGGL(rope_tab_kernel, dim3((T_ * DH_ + 255) / 256), dim3(256), 0, stream, ct, st);
    hipLaunchKernelGGL(qkv_rope_kernel, dim3(9, 256), dim3(256), 0, stream,
                       x, wq, wk, wv, ct, st, q_ws, k_ws, v_ws);
    hipLaunchKernelGGL(attn_kernel, dim3(32, HQ_, B_), dim3(256), 0, stream,
                       q_ws, k_ws, v_ws, ao);
    hipLaunchKernelGGL(out_proj_kernel, dim3(6, 256), dim3(256), 0, stream,
                       ao, wo, bo, out);
}

// Round 2
// 441.154 us; speedup vs baseline: 2.7448x; 2.7448x over previous
//
#include <hip/hip_runtime.h>
#include <math.h>

#define B_   8
#define T_   2048
#define NE_  384
#define HQ_  8
#define HKV_ 2
#define D_   48
#define DH_  24   // D/2

typedef __attribute__((ext_vector_type(8))) short bf16x8;
typedef __attribute__((ext_vector_type(4))) short bf16x4;
typedef __attribute__((ext_vector_type(4))) float f32x4;

static __device__ __forceinline__ short f2bf(float f) {
    union { float f; unsigned u; } v; v.f = f;
    unsigned r = (v.u + 0x7fffu + ((v.u >> 16) & 1u)) >> 16;
    return (short)r;
}

// ---------------- kernel 0: RoPE cos/sin table ----------------
__global__ void rope_tab_kernel(float* __restrict__ ct, float* __restrict__ st) {
    int i = blockIdx.x * 256 + threadIdx.x;
    if (i >= T_ * DH_) return;
    int t = i / DH_, j = i - t * DH_;
    double inv = pow(10000.0, -(double)(2 * j) / (double)D_);
    double ang = (double)t * inv;
    ct[i] = (float)cos(ang);
    st[i] = (float)sin(ang);
}

// ---------------- kernel 1: fused QKV GEMM + RoPE ----------------
__global__ __launch_bounds__(256) void qkv_rope_kernel(
    const float* __restrict__ x, const float* __restrict__ wq,
    const float* __restrict__ wk, const float* __restrict__ wv,
    const float* __restrict__ ct, const float* __restrict__ st,
    float* __restrict__ q_ws, float* __restrict__ k_ws, float* __restrict__ v_ws)
{
    const int tid = threadIdx.x;
    const int n0 = blockIdx.x * 64;   // 9 col tiles (576)
    const int m0 = blockIdx.y * 64;   // 256 row tiles
    __shared__ float As[32][64];      // A transposed: As[k][m]
    __shared__ float Bs[32][68];      // Bs[k][n], padded
    float acc[4][4] = {};
    const int tm0 = (tid >> 4) << 2;
    const int tn0 = (tid & 15) << 2;

    for (int kt = 0; kt < 384; kt += 32) {
#pragma unroll
        for (int p = 0; p < 2; ++p) {
            int f = tid + p * 256;
            int m = f & 63, kg = f >> 6;            // kg: 0..7
            float4 a4 = *(const float4*)&x[(size_t)(m0 + m) * NE_ + kt + kg * 4];
            As[kg * 4 + 0][m] = a4.x; As[kg * 4 + 1][m] = a4.y;
            As[kg * 4 + 2][m] = a4.z; As[kg * 4 + 3][m] = a4.w;
        }
#pragma unroll
        for (int p = 0; p < 2; ++p) {
            int f = tid + p * 256;
            int kk = f >> 4, ncg = f & 15;
            int n = n0 + ncg * 4;
            int kr = kt + kk;
            float4 b4;
            if (n < 384)      b4 = *(const float4*)&wq[(size_t)kr * 384 + n];
            else if (n < 480) b4 = *(const float4*)&wk[(size_t)kr * 96 + (n - 384)];
            else              b4 = *(const float4*)&wv[(size_t)kr * 96 + (n - 480)];
            *(float4*)&Bs[kk][ncg * 4] = b4;
        }
        __syncthreads();
#pragma unroll
        for (int kk = 0; kk < 32; ++kk) {
            float4 a4 = *(const float4*)&As[kk][tm0];
            float4 b4 = *(const float4*)&Bs[kk][tn0];
            float a[4] = {a4.x, a4.y, a4.z, a4.w};
            float b[4] = {b4.x, b4.y, b4.z, b4.w};
#pragma unroll
            for (int i = 0; i < 4; ++i)
#pragma unroll
                for (int j = 0; j < 4; ++j)
                    acc[i][j] += a[i] * b[j];
        }
        __syncthreads();
    }

#pragma unroll
    for (int i = 0; i < 4; ++i) {
        int m = m0 + tm0 + i;
        int b = m >> 11;          // /T_
        int t = m & 2047;
#pragma unroll
        for (int jp = 0; jp < 4; jp += 2) {
            int n = n0 + tn0 + jp;
            float e = acc[i][jp], o = acc[i][jp + 1];
            if (n < 384) {                       // q
                int h = n / 48, d = n % 48, fi = d >> 1;
                float c = ct[t * DH_ + fi], s = st[t * DH_ + fi];
                size_t base = ((size_t)(b * HQ_ + h) * T_ + t) * D_ + d;
                q_ws[base]     = e * c - o * s;
                q_ws[base + 1] = e * s + o * c;
            } else if (n < 480) {                // k
                int nn = n - 384;
                int h = nn / 48, d = nn % 48, fi = d >> 1;
                float c = ct[t * DH_ + fi], s = st[t * DH_ + fi];
                size_t base = ((size_t)(b * HKV_ + h) * T_ + t) * D_ + d;
                k_ws[base]     = e * c - o * s;
                k_ws[base + 1] = e * s + o * c;
            } else {                             // v
                int nn = n - 480;
                int h = nn / 48, d = nn % 48;
                size_t base = ((size_t)(b * HKV_ + h) * T_ + t) * D_ + d;
                v_ws[base]     = e;
                v_ws[base + 1] = o;
            }
        }
    }
}

// ---------------- kernel 2: MFMA flash attention (causal GQA) ----------------
// S^T = K·Q^T via mfma_f32_16x16x32_bf16: C frag (col=q=lane&15, row=k=4u+reg)
// is directly the A-frag layout of mfma_f32_16x16x16bf16_1k for the PV matmul.
// Wave w owns q columns 16w..16w+15; softmax state per-lane, shfl_xor reduced.
#define PITCH 72   // bf16 pitch: 144B = 16B-aligned rows, conflict-benign
__global__ __launch_bounds__(256) void attn_kernel(
    const float* __restrict__ q_ws, const float* __restrict__ k_ws,
    const float* __restrict__ v_ws, float* __restrict__ ao)
{
    const int tid = threadIdx.x;
    const int qt = 31 - blockIdx.x;     // long blocks dispatch first
    const int h  = blockIdx.y;
    const int b  = blockIdx.z;
    const int hk = h >> 2;              // GROUP=4

    __shared__ short Qs[64 * PITCH];    // Qs[q][d], d padded to 64
    __shared__ short Ks[64 * PITCH];    // Ks[k][d], d padded to 64
    __shared__ short Vt[48 * PITCH];    // Vt[d][k]  (transposed V)

    const float qscale = 0.14433756729740643f;  // 1/sqrt(48)

    // zero d-pad cols 48..63 of Qs, Ks (staging never writes them)
    {
        int row = tid & 63, part = tid >> 6;    // part 0..3
        *(unsigned long long*)&Qs[row * PITCH + 48 + part * 4] = 0ULL;
        *(unsigned long long*)&Ks[row * PITCH + 48 + part * 4] = 0ULL;
    }
    // stage Q (scaled, f32 -> bf16)
    {
        const float* qb = q_ws + ((size_t)(b * HQ_ + h) * T_ + qt * 64) * D_;
#pragma unroll
        for (int p = 0; p < 3; ++p) {
            int f = tid + p * 256;
            int row = f & 63, kg = f >> 6;       // kg 0..11
            float4 v4 = *(const float4*)&qb[row * 48 + kg * 4];
            bf16x4 pk = { f2bf(v4.x * qscale), f2bf(v4.y * qscale),
                          f2bf(v4.z * qscale), f2bf(v4.w * qscale) };
            *(bf16x4*)&Qs[row * PITCH + kg * 4] = pk;
        }
    }
    __syncthreads();

    const int lane = tid & 63;
    const int w = tid >> 6;             // wave id: q cols 16w..16w+15
    const int c = lane & 15;            // q col within tile
    const int u = lane >> 4;            // quad

    // Q fragments, resident across the whole K loop
    bf16x8 qf0 = *(bf16x8*)&Qs[(16 * w + c) * PITCH + 8 * u];
    bf16x8 qf1 = *(bf16x8*)&Qs[(16 * w + c) * PITCH + 32 + 8 * u];

    float m_s = -1e30f, l_s = 0.0f;
    f32x4 o0 = {0.f, 0.f, 0.f, 0.f};
    f32x4 o1 = {0.f, 0.f, 0.f, 0.f};
    f32x4 o2 = {0.f, 0.f, 0.f, 0.f};

    for (int jt = 0; jt <= qt; ++jt) {
        __syncthreads();   // previous iteration's readers done
        {
            const float* kb = k_ws + ((size_t)(b * HKV_ + hk) * T_ + jt * 64) * D_;
            const float* vb = v_ws + ((size_t)(b * HKV_ + hk) * T_ + jt * 64) * D_;
#pragma unroll
            for (int p = 0; p < 3; ++p) {
                int f = tid + p * 256;
                int row = f & 63, kg = f >> 6;
                float4 k4 = *(const float4*)&kb[row * 48 + kg * 4];
                bf16x4 pk = { f2bf(k4.x), f2bf(k4.y), f2bf(k4.z), f2bf(k4.w) };
                *(bf16x4*)&Ks[row * PITCH + kg * 4] = pk;
                float4 v4 = *(const float4*)&vb[row * 48 + kg * 4];
                Vt[(kg * 4 + 0) * PITCH + row] = f2bf(v4.x);
                Vt[(kg * 4 + 1) * PITCH + row] = f2bf(v4.y);
                Vt[(kg * 4 + 2) * PITCH + row] = f2bf(v4.z);
                Vt[(kg * 4 + 3) * PITCH + row] = f2bf(v4.w);
            }
        }
        __syncthreads();

        const bool diag = (jt == qt);
        const int mtmax = diag ? (w + 1) : 4;   // skip fully-masked k tiles

        // S^T tiles: s[mt] covers k rows 16mt+4u+reg, q col 16w+c
        f32x4 s[4];
#pragma unroll
        for (int mt = 0; mt < 4; ++mt) {
            if (mt < mtmax) {
                bf16x8 a0 = *(bf16x8*)&Ks[(16 * mt + c) * PITCH + 8 * u];
                bf16x8 a1 = *(bf16x8*)&Ks[(16 * mt + c) * PITCH + 32 + 8 * u];
                f32x4 acc = {0.f, 0.f, 0.f, 0.f};
                acc = __builtin_amdgcn_mfma_f32_16x16x32_bf16(a0, qf0, acc, 0, 0, 0);
                acc = __builtin_amdgcn_mfma_f32_16x16x32_bf16(a1, qf1, acc, 0, 0, 0);
                if (diag && mt == mtmax - 1) {   // diagonal 16x16 tile: k_loc>q_loc masked
#pragma unroll
                    for (int r = 0; r < 4; ++r)
                        acc[r] = (4 * u + r > c) ? -1e30f : acc[r];
                }
                s[mt] = acc;
            }
        }

        // online softmax (per q col, reduce across quads)
        float mloc = -1e30f;
#pragma unroll
        for (int mt = 0; mt < 4; ++mt)
            if (mt < mtmax)
                mloc = fmaxf(mloc, fmaxf(fmaxf(s[mt][0], s[mt][1]),
                                         fmaxf(s[mt][2], s[mt][3])));
        mloc = fmaxf(mloc, __shfl_xor(mloc, 16));
        mloc = fmaxf(mloc, __shfl_xor(mloc, 32));
        float mnew = fmaxf(m_s, mloc);
        float alpha = __expf(m_s - mnew);
        float psum = 0.0f;
        bf16x4 pf[4];
#pragma unroll
        for (int mt = 0; mt < 4; ++mt) {
            if (mt < mtmax) {
                float p0 = __expf(s[mt][0] - mnew);
                float p1 = __expf(s[mt][1] - mnew);
                float p2 = __expf(s[mt][2] - mnew);
                float p3 = __expf(s[mt][3] - mnew);
                psum += (p0 + p1) + (p2 + p3);
                pf[mt] = { f2bf(p0), f2bf(p1), f2bf(p2), f2bf(p3) };
            }
        }
        psum += __shfl_xor(psum, 16);
        psum += __shfl_xor(psum, 32);
        l_s = l_s * alpha + psum;
        m_s = mnew;

        // rescale O: alpha indexed by q col; O rows are q=4u+reg
        float a0 = __shfl(alpha, 4 * u + 0);
        float a1 = __shfl(alpha, 4 * u + 1);
        float a2 = __shfl(alpha, 4 * u + 2);
        float a3 = __shfl(alpha, 4 * u + 3);
        o0[0] *= a0; o0[1] *= a1; o0[2] *= a2; o0[3] *= a3;
        o1[0] *= a0; o1[1] *= a1; o1[2] *= a2; o1[3] *= a3;
        o2[0] *= a0; o2[1] *= a1; o2[2] *= a2; o2[3] *= a3;

        // PV: O[q][d] += P·V, P frags direct from registers
#pragma unroll
        for (int kt = 0; kt < 4; ++kt) {
            if (kt < mtmax) {
                bf16x4 b0 = *(bf16x4*)&Vt[(c) * PITCH + 16 * kt + 4 * u];
                bf16x4 b1 = *(bf16x4*)&Vt[(16 + c) * PITCH + 16 * kt + 4 * u];
                bf16x4 b2 = *(bf16x4*)&Vt[(32 + c) * PITCH + 16 * kt + 4 * u];
                o0 = __builtin_amdgcn_mfma_f32_16x16x16bf16_1k(pf[kt], b0, o0, 0, 0, 0);
                o1 = __builtin_amdgcn_mfma_f32_16x16x16bf16_1k(pf[kt], b1, o1, 0, 0, 0);
                o2 = __builtin_amdgcn_mfma_f32_16x16x16bf16_1k(pf[kt], b2, o2, 0, 0, 0);
            }
        }
    }

    // epilogue: O rows 16w+4u+reg, cols 16nt+c; divide by l (per q col -> shfl)
    float li = 1.0f / l_s;
    float l0 = __shfl(li, 4 * u + 0);
    float l1 = __shfl(li, 4 * u + 1);
    float l2 = __shfl(li, 4 * u + 2);
    float l3 = __shfl(li, 4 * u + 3);
    float lr[4] = { l0, l1, l2, l3 };
    f32x4 oo[3] = { o0, o1, o2 };
#pragma unroll
    for (int nt = 0; nt < 3; ++nt) {
#pragma unroll
        for (int r = 0; r < 4; ++r) {
            int t = qt * 64 + 16 * w + 4 * u + r;
            ao[((size_t)b * T_ + t) * NE_ + h * 48 + 16 * nt + c] = oo[nt][r] * lr[r];
        }
    }
}

// ---------------- kernel 3: out projection + bias ----------------
__global__ __launch_bounds__(256) void out_proj_kernel(
    const float* __restrict__ A, const float* __restrict__ W,
    const float* __restrict__ bias, float* __restrict__ out)
{
    const int tid = threadIdx.x;
    const int n0 = blockIdx.x * 64;   // 6 col tiles
    const int m0 = blockIdx.y * 64;   // 256 row tiles
    __shared__ float As[32][64];
    __shared__ float Bs[32][68];
    float acc[4][4] = {};
    const int tm0 = (tid >> 4) << 2;
    const int tn0 = (tid & 15) << 2;

    for (int kt = 0; kt < 384; kt += 32) {
#pragma unroll
        for (int p = 0; p < 2; ++p) {
            int f = tid + p * 256;
            int m = f & 63, kg = f >> 6;
            float4 a4 = *(const float4*)&A[(size_t)(m0 + m) * 384 + kt + kg * 4];
            As[kg * 4 + 0][m] = a4.x; As[kg * 4 + 1][m] = a4.y;
            As[kg * 4 + 2][m] = a4.z; As[kg * 4 + 3][m] = a4.w;
        }
#pragma unroll
        for (int p = 0; p < 2; ++p) {
            int f = tid + p * 256;
            int kk = f >> 4, ncg = f & 15;
            float4 b4 = *(const float4*)&W[(size_t)(kt + kk) * 384 + n0 + ncg * 4];
            *(float4*)&Bs[kk][ncg * 4] = b4;
        }
        __syncthreads();
#pragma unroll
        for (int kk = 0; kk < 32; ++kk) {
            float4 a4 = *(const float4*)&As[kk][tm0];
            float4 b4 = *(const float4*)&Bs[kk][tn0];
            float a[4] = {a4.x, a4.y, a4.z, a4.w};
            float b[4] = {b4.x, b4.y, b4.z, b4.w};
#pragma unroll
            for (int i = 0; i < 4; ++i)
#pragma unroll
                for (int j = 0; j < 4; ++j)
                    acc[i][j] += a[i] * b[j];
        }
        __syncthreads();
    }

    float4 bv = *(const float4*)&bias[n0 + tn0];
#pragma unroll
    for (int i = 0; i < 4; ++i) {
        size_t row = m0 + tm0 + i;
        float4 r = make_float4(acc[i][0] + bv.x, acc[i][1] + bv.y,
                               acc[i][2] + bv.z, acc[i][3] + bv.w);
        *(float4*)&out[row * 384 + n0 + tn0] = r;
    }
}

// ---------------- launcher ----------------
extern "C" void kernel_launch(void* const* d_in, const int* in_sizes, int n_in,
                              void* d_out, int out_size, void* d_ws, size_t ws_size,
                              hipStream_t stream) {
    const float* x  = (const float*)d_in[0];
    const float* wq = (const float*)d_in[1];
    const float* wk = (const float*)d_in[2];
    const float* wv = (const float*)d_in[3];
    const float* wo = (const float*)d_in[4];
    const float* bo = (const float*)d_in[5];
    float* out = (float*)d_out;

    float* ws = (float*)d_ws;
    float* ct   = ws;                       // 2048*24
    float* st   = ct + T_ * DH_;            // 2048*24
    float* q_ws = st + T_ * DH_;            // 8*8*2048*48
    float* k_ws = q_ws + (size_t)B_ * HQ_  * T_ * D_;
    float* v_ws = k_ws + (size_t)B_ * HKV_ * T_ * D_;
    float* ao   = v_ws + (size_t)B_ * HKV_ * T_ * D_;

    hipLaunchKernelGGL(rope_tab_kernel, dim3((T_ * DH_ + 255) / 256), dim3(256), 0, stream, ct, st);
    hipLaunchKernelGGL(qkv_rope_kernel, dim3(9, 256), dim3(256), 0, stream,
                       x, wq, wk, wv, ct, st, q_ws, k_ws, v_ws);
    hipLaunchKernelGGL(attn_kernel, dim3(32, HQ_, B_), dim3(256), 0, stream,
                       q_ws, k_ws, v_ws, ao);
    hipLaunchKernelGGL(out_proj_kernel, dim3(6, 256), dim3(256), 0, stream,
                       ao, wo, bo, out);
}

// Round 3
// 297.048 us; speedup vs baseline: 4.0764x; 1.4851x over previous
//
#include <hip/hip_runtime.h>
#include <math.h>

#define B_   8
#define T_   2048
#define NE_  384
#define HQ_  8
#define HKV_ 2
#define D_   48
#define DH_  24   // D/2

typedef __attribute__((ext_vector_type(8))) short bf16x8;
typedef __attribute__((ext_vector_type(4))) short bf16x4;
typedef __attribute__((ext_vector_type(4))) float f32x4;

static __device__ __forceinline__ short f2bf(float f) {
    union { float f; unsigned u; } v; v.f = f;
    unsigned r = (v.u + 0x7fffu + ((v.u >> 16) & 1u)) >> 16;
    return (short)r;
}

// ---------------- kernel 0: prep (convert + transpose + rope table) --------
// blocks [0,6144):   x f32 -> xb bf16 (float4 granularity)
// blocks [6144,7008): wq|wk|wv -> wt[n][k] bf16 (transposed, packed n=0..575)
// blocks [7008,7584): wo -> wot[n][k] bf16
// blocks [7584,7776): rope cos/sin tables (f32)
__global__ __launch_bounds__(256) void prep_kernel(
    const float* __restrict__ x, const float* __restrict__ wq,
    const float* __restrict__ wk, const float* __restrict__ wv,
    const float* __restrict__ wo,
    short* __restrict__ xb, short* __restrict__ wt, short* __restrict__ wot,
    float* __restrict__ ct, float* __restrict__ st)
{
    const int bid = blockIdx.x, tid = threadIdx.x;
    if (bid < 6144) {
        int i = bid * 256 + tid;                 // float4 index, 1572864 total
        float4 v = ((const float4*)x)[i];
        bf16x4 o = { f2bf(v.x), f2bf(v.y), f2bf(v.z), f2bf(v.w) };
        *(bf16x4*)&xb[(size_t)i * 4] = o;
    } else if (bid < 7008) {
        int e = (bid - 6144) * 256 + tid;        // < 221184
        int n = e / 384, k = e - n * 384;
        float s = (n < 384) ? wq[(size_t)k * 384 + n]
                : (n < 480) ? wk[(size_t)k * 96 + (n - 384)]
                            : wv[(size_t)k * 96 + (n - 480)];
        wt[e] = f2bf(s);
    } else if (bid < 7584) {
        int e = (bid - 7008) * 256 + tid;        // < 147456
        int n = e / 384, k = e - n * 384;
        wot[e] = f2bf(wo[(size_t)k * 384 + n]);
    } else {
        int i = (bid - 7584) * 256 + tid;        // < 49152
        int t = i / DH_, j = i - t * DH_;
        double inv = pow(10000.0, -(double)(2 * j) / (double)D_);
        double ang = (double)t * inv;
        ct[i] = (float)cos(ang);
        st[i] = (float)sin(ang);
    }
}

// ---------------- kernel 1: QKV MFMA GEMM + fused RoPE ----------------
// C[16384 x 576] = xb · wt^T  (wt is [n][k]).  Tiles 128x64, 4 waves.
// Epilogue: RoPE via shfl_xor(1) (d-pairs are adjacent lanes), writes
// qb/kb bf16 d-padded to 64 (pads pre-zeroed), v transposed to vtb[d][t].
#define GP 40   // LDS pitch in shorts: 80B rows -> 2-way banking (free)
__global__ __launch_bounds__(256) void qkv_gemm_kernel(
    const short* __restrict__ xb, const short* __restrict__ wt,
    const float* __restrict__ ct, const float* __restrict__ st,
    short* __restrict__ qb, short* __restrict__ kb, short* __restrict__ vtb)
{
    const int tid = threadIdx.x;
    const int n0 = blockIdx.x * 64;     // 9 tiles
    const int m0 = blockIdx.y * 128;    // 128 tiles
    __shared__ short As[128 * GP];
    __shared__ short Bs[64 * GP];
    const int lane = tid & 63, w = tid >> 6;
    const int c = lane & 15, u = lane >> 4;
    const int mo = (w & 1) * 64, no = (w >> 1) * 32;
    f32x4 acc[4][2] = {};

    for (int kt = 0; kt < 384; kt += 32) {
        __syncthreads();
#pragma unroll
        for (int p = 0; p < 2; ++p) {           // A: 128 rows x 32k = 512 chunks
            int f = tid + p * 256;
            int row = f >> 2, j = f & 3;
            bf16x8 v = *(const bf16x8*)&xb[(size_t)(m0 + row) * 384 + kt + j * 8];
            *(bf16x8*)&As[row * GP + j * 8] = v;
        }
        {                                        // B: 64 rows x 32k = 256 chunks
            int row = tid >> 2, j = tid & 3;
            bf16x8 v = *(const bf16x8*)&wt[(size_t)(n0 + row) * 384 + kt + j * 8];
            *(bf16x8*)&Bs[row * GP + j * 8] = v;
        }
        __syncthreads();
        bf16x8 af[4], bfr[2];
#pragma unroll
        for (int i = 0; i < 4; ++i) af[i] = *(bf16x8*)&As[(mo + 16 * i + c) * GP + 8 * u];
#pragma unroll
        for (int j = 0; j < 2; ++j) bfr[j] = *(bf16x8*)&Bs[(no + 16 * j + c) * GP + 8 * u];
#pragma unroll
        for (int i = 0; i < 4; ++i)
#pragma unroll
            for (int j = 0; j < 2; ++j)
                acc[i][j] = __builtin_amdgcn_mfma_f32_16x16x32_bf16(af[i], bfr[j], acc[i][j], 0, 0, 0);
    }

    const float qscale = 0.14433756729740643f;  // 1/sqrt(48)
#pragma unroll
    for (int i = 0; i < 4; ++i) {
#pragma unroll
        for (int j = 0; j < 2; ++j) {
            int n = n0 + no + 16 * j + c;        // region uniform per 16-wide subtile
            int mb = m0 + mo + 16 * i + 4 * u;
            int b = mb >> 11;
            int t0 = mb & 2047;
            if (n < 480) {                       // q or k: RoPE
                int nn = (n < 384) ? n : n - 384;
                int h = nn / 48, d = nn - h * 48;
                int fi = d >> 1;
                float sgn = (d & 1) ? 1.0f : -1.0f;
                float scl = (n < 384) ? qscale : 1.0f;
                short* dst = (n < 384) ? qb : kb;
                size_t base = (n < 384)
                    ? ((size_t)(b * HQ_ + h) * T_ + t0) * 64 + d
                    : ((size_t)(b * HKV_ + h) * T_ + t0) * 64 + d;
#pragma unroll
                for (int r = 0; r < 4; ++r) {
                    float val = acc[i][j][r];
                    float part = __shfl_xor(val, 1);
                    float cs = ct[(t0 + r) * DH_ + fi], sn = st[(t0 + r) * DH_ + fi];
                    dst[base + (size_t)r * 64] = f2bf((val * cs + sgn * part * sn) * scl);
                }
            } else {                             // v: no rope, transposed store
                int nn = n - 480;
                int h = nn / 48, d = nn - h * 48;
                ushort4 pk;
                pk.x = (unsigned short)f2bf(acc[i][j][0]);
                pk.y = (unsigned short)f2bf(acc[i][j][1]);
                pk.z = (unsigned short)f2bf(acc[i][j][2]);
                pk.w = (unsigned short)f2bf(acc[i][j][3]);
                *(ushort4*)&vtb[((size_t)(b * HKV_ + h) * D_ + d) * T_ + t0] = pk;
            }
        }
    }
}

// ---------------- kernel 2: MFMA flash attention (bf16 inputs) -------------
#define PITCH 72
__global__ __launch_bounds__(256) void attn_kernel(
    const short* __restrict__ qb, const short* __restrict__ kb,
    const short* __restrict__ vtb, short* __restrict__ aob)
{
    const int tid = threadIdx.x;
    const int qt = 31 - blockIdx.x;     // long blocks dispatch first
    const int h  = blockIdx.y;
    const int b  = blockIdx.z;
    const int hk = h >> 2;              // GROUP=4

    __shared__ short Qs[64 * PITCH];    // Qs[q][d64]
    __shared__ short Ks[64 * PITCH];    // Ks[k][d64]
    __shared__ short Vt[48 * PITCH];    // Vt[d][k]

    // stage Q (already bf16, scaled, roped; d-pad pre-zeroed in global)
    {
        const short* qsrc = qb + ((size_t)(b * HQ_ + h) * T_ + qt * 64) * 64;
#pragma unroll
        for (int p = 0; p < 2; ++p) {
            int f = tid + p * 256;
            int row = f >> 3, j = f & 7;
            bf16x8 v = *(const bf16x8*)&qsrc[row * 64 + j * 8];
            *(bf16x8*)&Qs[row * PITCH + j * 8] = v;
        }
    }
    __syncthreads();

    const int lane = tid & 63;
    const int w = tid >> 6;             // wave id: q cols 16w..16w+15
    const int c = lane & 15;
    const int u = lane >> 4;

    bf16x8 qf0 = *(bf16x8*)&Qs[(16 * w + c) * PITCH + 8 * u];
    bf16x8 qf1 = *(bf16x8*)&Qs[(16 * w + c) * PITCH + 32 + 8 * u];

    float m_s = -1e30f, l_s = 0.0f;
    f32x4 o0 = {0.f, 0.f, 0.f, 0.f};
    f32x4 o1 = {0.f, 0.f, 0.f, 0.f};
    f32x4 o2 = {0.f, 0.f, 0.f, 0.f};

    for (int jt = 0; jt <= qt; ++jt) {
        __syncthreads();
        {
            const short* ksrc = kb + ((size_t)(b * HKV_ + hk) * T_ + jt * 64) * 64;
            const short* vsrc = vtb + ((size_t)(b * HKV_ + hk) * D_) * T_ + jt * 64;
#pragma unroll
            for (int p = 0; p < 2; ++p) {
                int f = tid + p * 256;
                int row = f >> 3, j = f & 7;
                bf16x8 kv = *(const bf16x8*)&ksrc[row * 64 + j * 8];
                *(bf16x8*)&Ks[row * PITCH + j * 8] = kv;
            }
            for (int f = tid; f < 384; f += 256) {   // 48 d-rows x 8 chunks
                int row = f >> 3, j = f & 7;
                bf16x8 vv = *(const bf16x8*)&vsrc[(size_t)row * T_ + j * 8];
                *(bf16x8*)&Vt[row * PITCH + j * 8] = vv;
            }
        }
        __syncthreads();

        const bool diag = (jt == qt);
        const int mtmax = diag ? (w + 1) : 4;

        f32x4 s[4];
#pragma unroll
        for (int mt = 0; mt < 4; ++mt) {
            if (mt < mtmax) {
                bf16x8 a0 = *(bf16x8*)&Ks[(16 * mt + c) * PITCH + 8 * u];
                bf16x8 a1 = *(bf16x8*)&Ks[(16 * mt + c) * PITCH + 32 + 8 * u];
                f32x4 a = {0.f, 0.f, 0.f, 0.f};
                a = __builtin_amdgcn_mfma_f32_16x16x32_bf16(a0, qf0, a, 0, 0, 0);
                a = __builtin_amdgcn_mfma_f32_16x16x32_bf16(a1, qf1, a, 0, 0, 0);
                if (diag && mt == mtmax - 1) {
#pragma unroll
                    for (int r = 0; r < 4; ++r)
                        a[r] = (4 * u + r > c) ? -1e30f : a[r];
                }
                s[mt] = a;
            }
        }

        float mloc = -1e30f;
#pragma unroll
        for (int mt = 0; mt < 4; ++mt)
            if (mt < mtmax)
                mloc = fmaxf(mloc, fmaxf(fmaxf(s[mt][0], s[mt][1]),
                                         fmaxf(s[mt][2], s[mt][3])));
        mloc = fmaxf(mloc, __shfl_xor(mloc, 16));
        mloc = fmaxf(mloc, __shfl_xor(mloc, 32));
        float mnew = fmaxf(m_s, mloc);
        float alpha = __expf(m_s - mnew);
        float psum = 0.0f;
        bf16x4 pf[4];
#pragma unroll
        for (int mt = 0; mt < 4; ++mt) {
            if (mt < mtmax) {
                float p0 = __expf(s[mt][0] - mnew);
                float p1 = __expf(s[mt][1] - mnew);
                float p2 = __expf(s[mt][2] - mnew);
                float p3 = __expf(s[mt][3] - mnew);
                psum += (p0 + p1) + (p2 + p3);
                pf[mt] = { f2bf(p0), f2bf(p1), f2bf(p2), f2bf(p3) };
            }
        }
        psum += __shfl_xor(psum, 16);
        psum += __shfl_xor(psum, 32);
        l_s = l_s * alpha + psum;
        m_s = mnew;

        float a0 = __shfl(alpha, 4 * u + 0);
        float a1 = __shfl(alpha, 4 * u + 1);
        float a2 = __shfl(alpha, 4 * u + 2);
        float a3 = __shfl(alpha, 4 * u + 3);
        o0[0] *= a0; o0[1] *= a1; o0[2] *= a2; o0[3] *= a3;
        o1[0] *= a0; o1[1] *= a1; o1[2] *= a2; o1[3] *= a3;
        o2[0] *= a0; o2[1] *= a1; o2[2] *= a2; o2[3] *= a3;

#pragma unroll
        for (int kt = 0; kt < 4; ++kt) {
            if (kt < mtmax) {
                bf16x4 b0 = *(bf16x4*)&Vt[(c) * PITCH + 16 * kt + 4 * u];
                bf16x4 b1 = *(bf16x4*)&Vt[(16 + c) * PITCH + 16 * kt + 4 * u];
                bf16x4 b2 = *(bf16x4*)&Vt[(32 + c) * PITCH + 16 * kt + 4 * u];
                o0 = __builtin_amdgcn_mfma_f32_16x16x16bf16_1k(pf[kt], b0, o0, 0, 0, 0);
                o1 = __builtin_amdgcn_mfma_f32_16x16x16bf16_1k(pf[kt], b1, o1, 0, 0, 0);
                o2 = __builtin_amdgcn_mfma_f32_16x16x16bf16_1k(pf[kt], b2, o2, 0, 0, 0);
            }
        }
    }

    float li = 1.0f / l_s;
    float l0 = __shfl(li, 4 * u + 0);
    float l1 = __shfl(li, 4 * u + 1);
    float l2 = __shfl(li, 4 * u + 2);
    float l3 = __shfl(li, 4 * u + 3);
    float lr[4] = { l0, l1, l2, l3 };
    f32x4 oo[3] = { o0, o1, o2 };
#pragma unroll
    for (int nt = 0; nt < 3; ++nt) {
#pragma unroll
        for (int r = 0; r < 4; ++r) {
            int t = qt * 64 + 16 * w + 4 * u + r;
            aob[((size_t)b * T_ + t) * NE_ + h * D_ + 16 * nt + c] = f2bf(oo[nt][r] * lr[r]);
        }
    }
}

// ---------------- kernel 3: out projection MFMA + bias ----------------
__global__ __launch_bounds__(256) void out_gemm_kernel(
    const short* __restrict__ aob, const short* __restrict__ wot,
    const float* __restrict__ bias, float* __restrict__ out)
{
    const int tid = threadIdx.x;
    const int n0 = blockIdx.x * 64;     // 6 tiles
    const int m0 = blockIdx.y * 128;    // 128 tiles
    __shared__ short As[128 * GP];
    __shared__ short Bs[64 * GP];
    const int lane = tid & 63, w = tid >> 6;
    const int c = lane & 15, u = lane >> 4;
    const int mo = (w & 1) * 64, no = (w >> 1) * 32;
    f32x4 acc[4][2] = {};

    for (int kt = 0; kt < 384; kt += 32) {
        __syncthreads();
#pragma unroll
        for (int p = 0; p < 2; ++p) {
            int f = tid + p * 256;
            int row = f >> 2, j = f & 3;
            bf16x8 v = *(const bf16x8*)&aob[(size_t)(m0 + row) * 384 + kt + j * 8];
            *(bf16x8*)&As[row * GP + j * 8] = v;
        }
        {
            int row = tid >> 2, j = tid & 3;
            bf16x8 v = *(const bf16x8*)&wot[(size_t)(n0 + row) * 384 + kt + j * 8];
            *(bf16x8*)&Bs[row * GP + j * 8] = v;
        }
        __syncthreads();
        bf16x8 af[4], bfr[2];
#pragma unroll
        for (int i = 0; i < 4; ++i) af[i] = *(bf16x8*)&As[(mo + 16 * i + c) * GP + 8 * u];
#pragma unroll
        for (int j = 0; j < 2; ++j) bfr[j] = *(bf16x8*)&Bs[(no + 16 * j + c) * GP + 8 * u];
#pragma unroll
        for (int i = 0; i < 4; ++i)
#pragma unroll
            for (int j = 0; j < 2; ++j)
                acc[i][j] = __builtin_amdgcn_mfma_f32_16x16x32_bf16(af[i], bfr[j], acc[i][j], 0, 0, 0);
    }

#pragma unroll
    for (int i = 0; i < 4; ++i) {
#pragma unroll
        for (int j = 0; j < 2; ++j) {
            int n = n0 + no + 16 * j + c;
            int mb = m0 + mo + 16 * i + 4 * u;
            float bv = bias[n];
#pragma unroll
            for (int r = 0; r < 4; ++r)
                out[(size_t)(mb + r) * 384 + n] = acc[i][j][r] + bv;
        }
    }
}

// ---------------- launcher ----------------
extern "C" void kernel_launch(void* const* d_in, const int* in_sizes, int n_in,
                              void* d_out, int out_size, void* d_ws, size_t ws_size,
                              hipStream_t stream) {
    const float* x  = (const float*)d_in[0];
    const float* wq = (const float*)d_in[1];
    const float* wk = (const float*)d_in[2];
    const float* wv = (const float*)d_in[3];
    const float* wo = (const float*)d_in[4];
    const float* bo = (const float*)d_in[5];
    float* out = (float*)d_out;

    float* ct  = (float*)d_ws;                       // 49152 f32
    float* st  = ct + 49152;                         // 49152 f32
    short* xb  = (short*)(st + 49152);               // 16384*384
    short* wt  = xb  + (size_t)16384 * 384;          // 576*384
    short* wot = wt  + (size_t)576 * 384;            // 384*384
    short* qb  = wot + (size_t)384 * 384;            // 8*8*2048*64 (d-padded)
    short* kb  = qb  + (size_t)B_ * HQ_  * T_ * 64;  // 8*2*2048*64 (d-padded)
    short* vtb = kb  + (size_t)B_ * HKV_ * T_ * 64;  // 8*2*48*2048 (transposed)
    short* aob = vtb + (size_t)B_ * HKV_ * D_ * T_;  // 16384*384
    // total ~50.4 MB

    hipLaunchKernelGGL(prep_kernel, dim3(7776), dim3(256), 0, stream,
                       x, wq, wk, wv, wo, xb, wt, wot, ct, st);
    // zero qb+kb (adjacent) so d-pad cols 48..63 are 0 for the MFMA K-dim
    hipMemsetAsync(qb, 0, ((size_t)B_ * HQ_ * T_ * 64 + (size_t)B_ * HKV_ * T_ * 64) * sizeof(short), stream);
    hipLaunchKernelGGL(qkv_gemm_kernel, dim3(9, 128), dim3(256), 0, stream,
                       xb, wt, ct, st, qb, kb, vtb);
    hipLaunchKernelGGL(attn_kernel, dim3(32, HQ_, B_), dim3(256), 0, stream,
                       qb, kb, vtb, aob);
    hipLaunchKernelGGL(out_gemm_kernel, dim3(6, 128), dim3(256), 0, stream,
                       aob, wot, bo, out);
}

// Round 6
// 282.498 us; speedup vs baseline: 4.2863x; 1.0515x over previous
//
#include <hip/hip_runtime.h>
#include <math.h>

#define B_   8
#define T_   2048
#define NE_  384
#define HQ_  8
#define HKV_ 2
#define D_   48
#define DH_  24   // D/2

typedef __attribute__((ext_vector_type(8))) short bf16x8;
typedef __attribute__((ext_vector_type(4))) short bf16x4;
typedef __attribute__((ext_vector_type(4))) float f32x4;

static __device__ __forceinline__ short f2bf(float f) {
    union { float f; unsigned u; } v; v.f = f;
    unsigned r = (v.u + 0x7fffu + ((v.u >> 16) & 1u)) >> 16;
    return (short)r;
}

// ---------------- kernel 0: prep (convert + transpose + rope table) --------
__global__ __launch_bounds__(256) void prep_kernel(
    const float* __restrict__ x, const float* __restrict__ wq,
    const float* __restrict__ wk, const float* __restrict__ wv,
    const float* __restrict__ wo,
    short* __restrict__ xb, short* __restrict__ wt, short* __restrict__ wot,
    float* __restrict__ ct, float* __restrict__ st)
{
    const int bid = blockIdx.x, tid = threadIdx.x;
    if (bid < 6144) {
        int i = bid * 256 + tid;                 // float4 index, 1572864 total
        float4 v = ((const float4*)x)[i];
        bf16x4 o = { f2bf(v.x), f2bf(v.y), f2bf(v.z), f2bf(v.w) };
        *(bf16x4*)&xb[(size_t)i * 4] = o;
    } else if (bid < 7008) {
        int e = (bid - 6144) * 256 + tid;        // < 221184
        int n = e / 384, k = e - n * 384;
        float s = (n < 384) ? wq[(size_t)k * 384 + n]
                : (n < 480) ? wk[(size_t)k * 96 + (n - 384)]
                            : wv[(size_t)k * 96 + (n - 480)];
        wt[e] = f2bf(s);
    } else if (bid < 7584) {
        int e = (bid - 7008) * 256 + tid;        // < 147456
        int n = e / 384, k = e - n * 384;
        wot[e] = f2bf(wo[(size_t)k * 384 + n]);
    } else {
        int i = (bid - 7584) * 256 + tid;        // < 49152
        int t = i / DH_, j = i - t * DH_;
        double inv = pow(10000.0, -(double)(2 * j) / (double)D_);
        double ang = (double)t * inv;
        ct[i] = (float)cos(ang);
        st[i] = (float)sin(ang);
    }
}

// ---------------- kernel 1: QKV MFMA GEMM + fused RoPE (R3-exact) ----------
#define GP 40   // LDS pitch in shorts: 80B rows -> 2-way banking (free)
__global__ __launch_bounds__(256) void qkv_gemm_kernel(
    const short* __restrict__ xb, const short* __restrict__ wt,
    const float* __restrict__ ct, const float* __restrict__ st,
    short* __restrict__ qb, short* __restrict__ kb, short* __restrict__ vtb)
{
    const int tid = threadIdx.x;
    const int n0 = blockIdx.x * 64;     // 9 tiles
    const int m0 = blockIdx.y * 128;    // 128 tiles
    __shared__ short As[128 * GP];
    __shared__ short Bs[64 * GP];
    const int lane = tid & 63, w = tid >> 6;
    const int c = lane & 15, u = lane >> 4;
    const int mo = (w & 1) * 64, no = (w >> 1) * 32;
    f32x4 acc[4][2] = {};

    for (int kt = 0; kt < 384; kt += 32) {
        __syncthreads();
#pragma unroll
        for (int p = 0; p < 2; ++p) {
            int f = tid + p * 256;
            int row = f >> 2, j = f & 3;
            bf16x8 v = *(const bf16x8*)&xb[(size_t)(m0 + row) * 384 + kt + j * 8];
            *(bf16x8*)&As[row * GP + j * 8] = v;
        }
        {
            int row = tid >> 2, j = tid & 3;
            bf16x8 v = *(const bf16x8*)&wt[(size_t)(n0 + row) * 384 + kt + j * 8];
            *(bf16x8*)&Bs[row * GP + j * 8] = v;
        }
        __syncthreads();
        bf16x8 af[4], bfr[2];
#pragma unroll
        for (int i = 0; i < 4; ++i) af[i] = *(bf16x8*)&As[(mo + 16 * i + c) * GP + 8 * u];
#pragma unroll
        for (int j = 0; j < 2; ++j) bfr[j] = *(bf16x8*)&Bs[(no + 16 * j + c) * GP + 8 * u];
#pragma unroll
        for (int i = 0; i < 4; ++i)
#pragma unroll
            for (int j = 0; j < 2; ++j)
                acc[i][j] = __builtin_amdgcn_mfma_f32_16x16x32_bf16(af[i], bfr[j], acc[i][j], 0, 0, 0);
    }

    const float qscale = 0.14433756729740643f;  // 1/sqrt(48)
#pragma unroll
    for (int i = 0; i < 4; ++i) {
#pragma unroll
        for (int j = 0; j < 2; ++j) {
            int n = n0 + no + 16 * j + c;        // region uniform per 16-wide subtile
            int mb = m0 + mo + 16 * i + 4 * u;
            int b = mb >> 11;
            int t0 = mb & 2047;
            if (n < 480) {                       // q or k: RoPE, 64-padded store
                int nn = (n < 384) ? n : n - 384;
                int h = nn / 48, d = nn - h * 48;
                int fi = d >> 1;
                float sgn = (d & 1) ? 1.0f : -1.0f;
                float scl = (n < 384) ? qscale : 1.0f;
                short* dst = (n < 384) ? qb : kb;
                size_t base = (n < 384)
                    ? ((size_t)(b * HQ_ + h) * T_ + t0) * 64 + d
                    : ((size_t)(b * HKV_ + h) * T_ + t0) * 64 + d;
#pragma unroll
                for (int r = 0; r < 4; ++r) {
                    float val = acc[i][j][r];
                    float part = __shfl_xor(val, 1);
                    float cs = ct[(t0 + r) * DH_ + fi], sn = st[(t0 + r) * DH_ + fi];
                    dst[base + (size_t)r * 64] = f2bf((val * cs + sgn * part * sn) * scl);
                }
            } else {                             // v: no rope, transposed store
                int nn = n - 480;
                int h = nn / 48, d = nn - h * 48;
                ushort4 pk;
                pk.x = (unsigned short)f2bf(acc[i][j][0]);
                pk.y = (unsigned short)f2bf(acc[i][j][1]);
                pk.z = (unsigned short)f2bf(acc[i][j][2]);
                pk.w = (unsigned short)f2bf(acc[i][j][3]);
                *(ushort4*)&vtb[((size_t)(b * HKV_ + h) * D_ + d) * T_ + t0] = pk;
            }
        }
    }
}

// ---------------- kernel 2: LDS-free head-fused MFMA flash attention -------
// Minimal diff vs R3's verified math: QK = two 16x16x32 MFMAs over 64-padded
// d (pad zeroed); fragments read straight from global (identical elements to
// R3's LDS staging); per-head logic duplicated for 2 heads; mtmax tile-skip
// and mask exactly as R3. No LDS, no barriers, no double-buffer.
__global__ __launch_bounds__(256, 2) void attn_kernel(
    const short* __restrict__ qb, const short* __restrict__ kb,
    const short* __restrict__ vtb, short* __restrict__ aob)
{
    const int tid = threadIdx.x;
    const int x  = blockIdx.x;          // 0..15: qt = 31-x then qt = x
    const int hk = blockIdx.y >> 1;     // 0..1
    const int gp = blockIdx.y & 1;      // head pair within group
    const int b  = blockIdx.z;
    const int lane = tid & 63;
    const int w = tid >> 6;             // q-subtile: q rows 16w..16w+15
    const int c = lane & 15;
    const int u = lane >> 4;

    const short* kbase = kb  + (size_t)(b * HKV_ + hk) * T_ * 64 + c * 64 + 8 * u;
    const short* vbase = vtb + (size_t)(b * HKV_ + hk) * D_ * T_ + c * T_ + 4 * u;

#pragma unroll 1
    for (int ph = 0; ph < 2; ++ph) {
        const int qt = ph ? x : 31 - x;     // complementary pair: 33 iters total
        bf16x8 qf0[2], qf1[2];
#pragma unroll
        for (int g = 0; g < 2; ++g) {
            int h = hk * 4 + gp * 2 + g;
            const short* qp = qb + ((size_t)(b * HQ_ + h) * T_ + qt * 64 + 16 * w + c) * 64;
            qf0[g] = *(const bf16x8*)(qp + 8 * u);          // d 0..31
            qf1[g] = *(const bf16x8*)(qp + 32 + 8 * u);     // d 32..63 (pad=0)
        }
        float m_s[2] = { -1e30f, -1e30f };
        float l_s[2] = { 0.f, 0.f };
        f32x4 o[2][3] = {};

#pragma unroll 1
        for (int jt = 0; jt <= qt; ++jt) {
            const bool diag = (jt == qt);
            const int mtmax = diag ? (w + 1) : 4;
            const short* kjt = kbase + jt * 4096;       // 64 rows * 64
            const short* vjt = vbase + jt * 64;

            bf16x8 klo[4], khi[4];
            bf16x4 vf[3][4];
#pragma unroll
            for (int mt = 0; mt < 4; ++mt) {
                if (mt < mtmax) {
                    klo[mt] = *(const bf16x8*)(kjt + mt * 1024);        // K[16mt+c][8u+i]
                    khi[mt] = *(const bf16x8*)(kjt + mt * 1024 + 32);   // d 32..63
                }
            }
#pragma unroll
            for (int nt = 0; nt < 3; ++nt)
#pragma unroll
                for (int k2 = 0; k2 < 4; ++k2)
                    if (k2 < mtmax)
                        vf[nt][k2] = *(const bf16x4*)(vjt + nt * 16 * T_ + k2 * 16);

#pragma unroll
            for (int g = 0; g < 2; ++g) {
                // S^T tiles: s[mt] = S^T[k=16mt+4u+r][q=16w+c]
                f32x4 s[4];
#pragma unroll
                for (int mt = 0; mt < 4; ++mt) {
                    if (mt < mtmax) {
                        f32x4 a = {0.f, 0.f, 0.f, 0.f};
                        a = __builtin_amdgcn_mfma_f32_16x16x32_bf16(klo[mt], qf0[g], a, 0, 0, 0);
                        a = __builtin_amdgcn_mfma_f32_16x16x32_bf16(khi[mt], qf1[g], a, 0, 0, 0);
                        if (diag && mt == mtmax - 1) {      // diagonal 16x16 tile
#pragma unroll
                            for (int r = 0; r < 4; ++r)
                                a[r] = (4 * u + r > c) ? -1e30f : a[r];
                        }
                        s[mt] = a;
                    }
                }

                float mloc = -1e30f;
#pragma unroll
                for (int mt = 0; mt < 4; ++mt)
                    if (mt < mtmax)
                        mloc = fmaxf(mloc, fmaxf(fmaxf(s[mt][0], s[mt][1]),
                                                 fmaxf(s[mt][2], s[mt][3])));
                mloc = fmaxf(mloc, __shfl_xor(mloc, 16));
                mloc = fmaxf(mloc, __shfl_xor(mloc, 32));
                float mnew = fmaxf(m_s[g], mloc);
                float alpha = __expf(m_s[g] - mnew);
                m_s[g] = mnew;
                float psum = 0.0f;
                bf16x4 pf[4];
#pragma unroll
                for (int mt = 0; mt < 4; ++mt) {
                    if (mt < mtmax) {
                        float p0 = __expf(s[mt][0] - mnew);
                        float p1 = __expf(s[mt][1] - mnew);
                        float p2 = __expf(s[mt][2] - mnew);
                        float p3 = __expf(s[mt][3] - mnew);
                        psum += (p0 + p1) + (p2 + p3);
                        pf[mt] = { f2bf(p0), f2bf(p1), f2bf(p2), f2bf(p3) };
                    }
                }
                psum += __shfl_xor(psum, 16);
                psum += __shfl_xor(psum, 32);
                l_s[g] = l_s[g] * alpha + psum;

                float a0 = __shfl(alpha, 4 * u + 0);
                float a1 = __shfl(alpha, 4 * u + 1);
                float a2 = __shfl(alpha, 4 * u + 2);
                float a3 = __shfl(alpha, 4 * u + 3);
#pragma unroll
                for (int nt = 0; nt < 3; ++nt) {
                    o[g][nt][0] *= a0; o[g][nt][1] *= a1;
                    o[g][nt][2] *= a2; o[g][nt][3] *= a3;
                }
#pragma unroll
                for (int k2 = 0; k2 < 4; ++k2) {
                    if (k2 < mtmax) {
#pragma unroll
                        for (int nt = 0; nt < 3; ++nt)
                            o[g][nt] = __builtin_amdgcn_mfma_f32_16x16x16bf16_1k(
                                pf[k2], vf[nt][k2], o[g][nt], 0, 0, 0);
                    }
                }
            }
        }

        // epilogue: O rows 16w+4u+r, cols 16nt+c (per head)
#pragma unroll
        for (int g = 0; g < 2; ++g) {
            int h = hk * 4 + gp * 2 + g;
            float li = 1.0f / l_s[g];
            float l0 = __shfl(li, 4 * u + 0);
            float l1 = __shfl(li, 4 * u + 1);
            float l2 = __shfl(li, 4 * u + 2);
            float l3 = __shfl(li, 4 * u + 3);
            float lr[4] = { l0, l1, l2, l3 };
#pragma unroll
            for (int nt = 0; nt < 3; ++nt)
#pragma unroll
                for (int r = 0; r < 4; ++r) {
                    int t = qt * 64 + 16 * w + 4 * u + r;
                    aob[((size_t)b * T_ + t) * NE_ + h * D_ + 16 * nt + c] =
                        f2bf(o[g][nt][r] * lr[r]);
                }
        }
    }
}

// ---------------- kernel 3: out projection MFMA + bias ----------------
__global__ __launch_bounds__(256) void out_gemm_kernel(
    const short* __restrict__ aob, const short* __restrict__ wot,
    const float* __restrict__ bias, float* __restrict__ out)
{
    const int tid = threadIdx.x;
    const int n0 = blockIdx.x * 64;     // 6 tiles
    const int m0 = blockIdx.y * 128;    // 128 tiles
    __shared__ short As[128 * GP];
    __shared__ short Bs[64 * GP];
    const int lane = tid & 63, w = tid >> 6;
    const int c = lane & 15, u = lane >> 4;
    const int mo = (w & 1) * 64, no = (w >> 1) * 32;
    f32x4 acc[4][2] = {};

    for (int kt = 0; kt < 384; kt += 32) {
        __syncthreads();
#pragma unroll
        for (int p = 0; p < 2; ++p) {
            int f = tid + p * 256;
            int row = f >> 2, j = f & 3;
            bf16x8 v = *(const bf16x8*)&aob[(size_t)(m0 + row) * 384 + kt + j * 8];
            *(bf16x8*)&As[row * GP + j * 8] = v;
        }
        {
            int row = tid >> 2, j = tid & 3;
            bf16x8 v = *(const bf16x8*)&wot[(size_t)(n0 + row) * 384 + kt + j * 8];
            *(bf16x8*)&Bs[row * GP + j * 8] = v;
        }
        __syncthreads();
        bf16x8 af[4], bfr[2];
#pragma unroll
        for (int i = 0; i < 4; ++i) af[i] = *(bf16x8*)&As[(mo + 16 * i + c) * GP + 8 * u];
#pragma unroll
        for (int j = 0; j < 2; ++j) bfr[j] = *(bf16x8*)&Bs[(no + 16 * j + c) * GP + 8 * u];
#pragma unroll
        for (int i = 0; i < 4; ++i)
#pragma unroll
            for (int j = 0; j < 2; ++j)
                acc[i][j] = __builtin_amdgcn_mfma_f32_16x16x32_bf16(af[i], bfr[j], acc[i][j], 0, 0, 0);
    }

#pragma unroll
    for (int i = 0; i < 4; ++i) {
#pragma unroll
        for (int j = 0; j < 2; ++j) {
            int n = n0 + no + 16 * j + c;
            int mb = m0 + mo + 16 * i + 4 * u;
            float bv = bias[n];
#pragma unroll
            for (int r = 0; r < 4; ++r)
                out[(size_t)(mb + r) * 384 + n] = acc[i][j][r] + bv;
        }
    }
}

// ---------------- launcher ----------------
extern "C" void kernel_launch(void* const* d_in, const int* in_sizes, int n_in,
                              void* d_out, int out_size, void* d_ws, size_t ws_size,
                              hipStream_t stream) {
    const float* x  = (const float*)d_in[0];
    const float* wq = (const float*)d_in[1];
    const float* wk = (const float*)d_in[2];
    const float* wv = (const float*)d_in[3];
    const float* wo = (const float*)d_in[4];
    const float* bo = (const float*)d_in[5];
    float* out = (float*)d_out;

    float* ct  = (float*)d_ws;                       // 49152 f32
    float* st  = ct + 49152;                         // 49152 f32
    short* xb  = (short*)(st + 49152);               // 16384*384
    short* wt  = xb  + (size_t)16384 * 384;          // 576*384
    short* wot = wt  + (size_t)576 * 384;            // 384*384
    short* qb  = wot + (size_t)384 * 384;            // 8*8*2048*64 (d-padded)
    short* kb  = qb  + (size_t)B_ * HQ_  * T_ * 64;  // 8*2*2048*64 (d-padded)
    short* vtb = kb  + (size_t)B_ * HKV_ * T_ * 64;  // 8*2*48*2048 (transposed)
    short* aob = vtb + (size_t)B_ * HKV_ * D_ * T_;  // 16384*384
    // total ~50.4 MB

    hipLaunchKernelGGL(prep_kernel, dim3(7776), dim3(256), 0, stream,
                       x, wq, wk, wv, wo, xb, wt, wot, ct, st);
    // zero qb+kb (adjacent) so d-pad cols 48..63 are 0 for the MFMA K-dim
    hipMemsetAsync(qb, 0, ((size_t)B_ * HQ_ * T_ * 64 + (size_t)B_ * HKV_ * T_ * 64) * sizeof(short), stream);
    hipLaunchKernelGGL(qkv_gemm_kernel, dim3(9, 128), dim3(256), 0, stream,
                       xb, wt, ct, st, qb, kb, vtb);
    hipLaunchKernelGGL(attn_kernel, dim3(16, 4, 8), dim3(256), 0, stream,
                       qb, kb, vtb, aob);
    hipLaunchKernelGGL(out_gemm_kernel, dim3(6, 128), dim3(256), 0, stream,
                       aob, wot, bo, out);
}